// Round 10
// baseline (48.776 us; speedup 1.0000x reference)
//
#include <hip/hip_runtime.h>

// Problem geometry (fixed by the reference)
#define HH    2160
#define WW    3840
#define CROPC 3
#define NN    (HH - 2*CROPC)   // 2154 output rows
#define WFLAT (WW * 3)         // 11520 flat columns

constexpr int TY    = 16;        // output rows per wave-strip
constexpr int OPW   = 46;        // output flat-cols per wave (64 lanes - 18 halo)
constexpr int WPB   = 4;         // independent waves per block (no barriers between)
constexpr int NTH   = 64 * WPB;  // 256
constexpr int OPB   = OPW * WPB; // 184 output flat-cols per block
constexpr int XROWS = TY + 6;    // 22 input rows per strip

// Single-instruction 3-input median
__device__ __forceinline__ float vmed3(float a, float b, float c) {
    float r;
    asm("v_med3_f32 %0, %1, %2, %3" : "=v"(r) : "v"(a), "v"(b), "v"(c));
    return r;
}
// 7-op median-of-5: med3(e, max(min(a,b),min(c,d)), min(max(a,b),max(c,d)))
// (identity verified on-HW in R9, absmax = 0)
__device__ __forceinline__ float med5_7(float a, float b, float c, float d, float e) {
    const float lo1 = fminf(a, b), hi1 = fmaxf(a, b);
    const float lo2 = fminf(c, d), hi2 = fmaxf(c, d);
    return vmed3(e, fmaxf(lo1, lo2), fminf(hi1, hi2));
}

__global__ __launch_bounds__(NTH, 8) void fused_median(const float* __restrict__ img,
                                                       float* __restrict__ out) {
    // Wave-autonomous: zero LDS, zero barriers. Lane <-> one flat column.
    const int tid  = threadIdx.x;
    const int lane = tid & 63;
    const int wv   = tid >> 6;
    const int r0   = blockIdx.y * TY;
    const int fp12 = blockIdx.x * OPB + wv * OPW + lane;  // = flat_col + 12, >= 0
    const int fl   = fp12 - 12;                           // lane's flat col (may be <0)
    const int ch   = fp12 % 3;                            // channel (12 % 3 == 0)
    const int cc   = min(max(fp12 / 3 - 4, 0), WW - 1);   // clamped img col
    const float* colp = img + (size_t)CROPC * WFLAT + (cc * 3 + ch);

    const int  ci       = fl / 3;                         // img col (valid for fl>=0)
    const bool store_ok = (lane >= 12) && (lane < 58) && (fl < WFLAT);

    // clamped shuffle source lanes (computed once; avoids UB on edge lanes)
    const int lm6 = max(lane - 6, 0), lm3 = max(lane - 3, 0);
    const int lp3 = min(lane + 3, 63), lp6 = min(lane + 6, 63);

    // Batch all 22 column loads (proven to pin the batch live: R7)
    float xv[XROWS];
    #pragma unroll
    for (int i = 0; i < XROWS; ++i) {
        const int rr = min(max(r0 - 4 + i, 0), NN - 1);   // wave-uniform
        xv[i] = colp[(size_t)rr * WFLAT];
    }
    asm volatile("" ::
        "v"(xv[0]),  "v"(xv[1]),  "v"(xv[2]),  "v"(xv[3]),  "v"(xv[4]),
        "v"(xv[5]),  "v"(xv[6]),  "v"(xv[7]),  "v"(xv[8]),  "v"(xv[9]),
        "v"(xv[10]), "v"(xv[11]), "v"(xv[12]), "v"(xv[13]), "v"(xv[14]),
        "v"(xv[15]), "v"(xv[16]), "v"(xv[17]), "v"(xv[18]), "v"(xv[19]),
        "v"(xv[20]), "v"(xv[21]));

    // Sliding vertical med5 (shared pair-sorts, R9) fused row-by-row with the
    // horizontal chain via in-wave shuffles -> result stored immediately.
    float lo0 = fminf(xv[0], xv[1]), hi0 = fmaxf(xv[0], xv[1]);
    float lo1 = fminf(xv[1], xv[2]), hi1 = fmaxf(xv[1], xv[2]);
    float vm2 = 0.f, vm1 = 0.f;
    #pragma unroll
    for (int s = 0; s < TY + 2; ++s) {
        const float lo2 = fminf(xv[s+2], xv[s+3]);
        const float hi2 = fmaxf(xv[s+2], xv[s+3]);
        const float vc  = vmed3(xv[s+4], fmaxf(lo0, lo2), fminf(hi0, hi2)); // v[r0+s-2]
        if (s >= 2) {
            const int rz = r0 + s - 2;
            // v2[rz] = med3(v[rz-2],v[rz-1],v[rz]); shift1 edge algebra:
            //  rz==0 -> 0 ; rz==1 -> med3(0,v0,v1) ; rz==NN-1 -> v[NN-2]
            float a = vm2, b = vm1;
            if (rz == NN - 1) a = b;
            if (rz == 1)      a = 0.f;
            if (rz == 0)    { a = 0.f; b = 0.f; }
            const float w = vmed3(a, b, vc);              // v2[rz] at this lane's col

            // horizontal med5 over cols ci-2..ci+2 (flat +/-3, +/-6; same channel)
            const float m6 = __shfl(w, lm6, 64);
            const float m3 = __shfl(w, lm3, 64);
            const float p3 = __shfl(w, lp3, 64);
            const float p6 = __shfl(w, lp6, 64);
            const float h0 = med5_7(m6, m3, p3, p6, w);   // h1[ci] (valid lanes 6..57)

            // shift1 + med3: h2[ci] = med3(h1[ci-2], h1[ci-1], h1[ci]) + edge algebra
            const float hm3 = __shfl(h0, lm3, 64);        // h1[ci-1]
            const float hm6 = __shfl(h0, lm6, 64);        // h1[ci-2]
            float A = hm6, B = hm3;
            if (ci == WW - 1) A = B;
            if (ci == 1)      A = 0.f;
            if (ci == 0)    { A = 0.f; B = 0.f; }
            const float o = vmed3(A, B, h0);

            if (store_ok && rz < NN)
                out[(size_t)rz * WFLAT + fl] = o;         // 46 contiguous dwords/wave
        }
        lo0 = lo1; hi0 = hi1; lo1 = lo2; hi1 = hi2;
        vm2 = vm1; vm1 = vc;
    }
}

extern "C" void kernel_launch(void* const* d_in, const int* in_sizes, int n_in,
                              void* d_out, int out_size, void* d_ws, size_t ws_size,
                              hipStream_t stream) {
    const float* img = (const float*)d_in[0];   // (2160, 3840, 3) fp32
    // d_in[1] = mask (unused by reference), d_in[2] = vertical_size (== 5)
    float* out = (float*)d_out;                 // (2154, 3840, 3) fp32
    dim3 grid((WFLAT + OPB - 1) / OPB,          // 63 strips of 184 cols
              (NN + TY - 1) / TY);              // 135 row bands
    fused_median<<<grid, NTH, 0, stream>>>(img, out);
}